// Round 10
// baseline (496.894 us; speedup 1.0000x reference)
//
#include <hip/hip_runtime.h>

#define IN_CH 128
#define HID   256
#define PB_VT 16            // 4096 edges per partition block
#define BCAP  6144          // per-bucket capacity (mean 4096, sd 64 -> +32 sd)

typedef __attribute__((ext_vector_type(8))) short bf16x8;
typedef __attribute__((ext_vector_type(4))) float f32x4;
typedef __attribute__((ext_vector_type(2))) float f32x2;
typedef __attribute__((ext_vector_type(8))) unsigned short ushort8;

__device__ __forceinline__ ushort f2b(float f) {
    unsigned u = __float_as_uint(f);
    unsigned r = (u + 0x7fffu + ((u >> 16) & 1u)) >> 16;
    return (ushort)r;
}
__device__ __forceinline__ float b2f(ushort h) {
    return __uint_as_float(((unsigned)h) << 16);
}
// 8 packed fp8 (e4m3, HW cvt) -> 8 f32
__device__ __forceinline__ void fp8x8_to_f32(uint2 v, float f[8]) {
    f32x2 a = __builtin_amdgcn_cvt_pk_f32_fp8((int)v.x, false);
    f32x2 b = __builtin_amdgcn_cvt_pk_f32_fp8((int)v.x, true);
    f32x2 c = __builtin_amdgcn_cvt_pk_f32_fp8((int)v.y, false);
    f32x2 d = __builtin_amdgcn_cvt_pk_f32_fp8((int)v.y, true);
    f[0] = a[0]; f[1] = a[1]; f[2] = b[0]; f[3] = b[1];
    f[4] = c[0]; f[5] = c[1]; f[6] = d[0]; f[7] = d[1];
}
// 16 packed fp8 -> 16 f32
__device__ __forceinline__ void fp8x16_to_f32(uint4 v, float f[16]) {
    uint2 lo; lo.x = v.x; lo.y = v.y;
    uint2 hi; hi.x = v.z; hi.y = v.w;
    fp8x8_to_f32(lo, f);
    fp8x8_to_f32(hi, f + 8);
}

// ================= fused bf16+fp8 conversions + counter zeroing (round-5 proven) =================
__device__ __forceinline__ void prep_w_body(const float* __restrict__ Wl,
                                            const float* __restrict__ Wr,
                                            ushort* __restrict__ Wt,
                                            int KH, bool permK, int idx) {
    int ktot = 2 * KH;
    if (idx >= 256 * ktot) return;
    int n = idx / ktot, k = idx % ktot;
    int kh = (k < KH) ? k : (k - KH);
    int c = kh;
    if (permK) {
        int j = kh & 63;
        c = (kh & ~63) | ((j & 3) * 16 + (j >> 2));
    }
    float v = (k < KH) ? Wl[(size_t)c * 256 + n] : Wr[(size_t)c * 256 + n];
    Wt[idx] = f2b(v);
}

__global__ __launch_bounds__(256)
void fused_cvt_prep(const float* __restrict__ x, ushort* __restrict__ xb,
                    unsigned char* __restrict__ x8, int n4, int nCvt,
                    const float* __restrict__ W1l, const float* __restrict__ W1r, ushort* __restrict__ Wt1,
                    const float* __restrict__ W2l, const float* __restrict__ W2r, ushort* __restrict__ Wt2,
                    int* __restrict__ bucketCntG, int* __restrict__ bucketCntP) {
    int b = blockIdx.x;
    int t = threadIdx.x;
    if (b < nCvt) {
        int i = b * 256 + t;
        if (i < n4) {
            float4 v = ((const float4*)x)[i];
            ushort4 u;
            u.x = f2b(v.x); u.y = f2b(v.y); u.z = f2b(v.z); u.w = f2b(v.w);
            ((ushort4*)xb)[i] = u;
            int p = __builtin_amdgcn_cvt_pk_fp8_f32(v.x, v.y, 0, false);
            p = __builtin_amdgcn_cvt_pk_fp8_f32(v.z, v.w, p, true);
            ((unsigned*)x8)[i] = (unsigned)p;
        }
    } else if (b < nCvt + 256) {
        prep_w_body(W1l, W1r, Wt1, IN_CH, false, (b - nCvt) * 256 + t);
    } else if (b < nCvt + 256 + 512) {
        prep_w_body(W2l, W2r, Wt2, HID, true, (b - nCvt - 256) * 256 + t);
    } else {
        bucketCntG[t] = 0;
        bucketCntG[t + 256] = 0;
        bucketCntP[t] = 0;
        bucketCntP[t + 256] = 0;
    }
}

// ================= single-pass reservation scatter (round-4/5 proven) =================
__global__ __launch_bounds__(256)
void scatter_reserve_kernel(const int* __restrict__ src, const int* __restrict__ dst,
                            const int* __restrict__ edges,
                            int* __restrict__ bucketCntG, int* __restrict__ bucketCntP,
                            unsigned* __restrict__ tmpG, unsigned long long* __restrict__ tmpP,
                            int E, int E2, int NBUK, int NBG) {
    __shared__ int hist[512];
    __shared__ int cur[512];
    int t = threadIdx.x;
    bool isG = (int)blockIdx.x < NBG;
    int blk = isG ? blockIdx.x : blockIdx.x - NBG;
    for (int i = t; i < NBUK; i += 256) hist[i] = 0;
    __syncthreads();
    long long e0 = (long long)blk * (256 * PB_VT);
    if (isG) {
#pragma unroll
        for (int i = 0; i < PB_VT; i++) {
            long long e = e0 + i * 256 + t;
            if (e < E) atomicAdd(&hist[dst[e] >> 8], 1);
        }
    } else {
#pragma unroll
        for (int i = 0; i < PB_VT; i++) {
            long long e = e0 + i * 256 + t;
            if (e < E2) atomicAdd(&hist[edges[e * 2] >> 8], 1);
        }
    }
    __syncthreads();
    int* bcnt = isG ? bucketCntG : bucketCntP;
    for (int i = t; i < NBUK; i += 256) {
        int hc = hist[i];
        cur[i] = (hc > 0) ? atomicAdd(&bcnt[i], hc) : 0;
    }
    __syncthreads();
    if (isG) {
#pragma unroll
        for (int i = 0; i < PB_VT; i++) {
            long long e = e0 + i * 256 + t;
            if (e < E) {
                int d = dst[e];
                int bk = d >> 8;
                int pos = atomicAdd(&cur[bk], 1);       // LDS atomic
                tmpG[(size_t)bk * BCAP + pos] = ((unsigned)src[e] << 8) | (unsigned)(d & 255);
            }
        }
    } else {
#pragma unroll
        for (int i = 0; i < PB_VT; i++) {
            long long e = e0 + i * 256 + t;
            if (e < E2) {
                int2 ab = *(const int2*)(edges + e * 2);
                int bk = ab.x >> 8;
                int pos = atomicAdd(&cur[bk], 1);
                tmpP[(size_t)bk * BCAP + pos] = ((unsigned long long)(unsigned)(ab.x & 255) << 56)
                                              | ((unsigned long long)(unsigned)ab.y << 32)
                                              | (unsigned)e;
            }
        }
    }
}

// ================= per-bucket sort into padded per-node lists (round-4 proven) =================
__global__ __launch_bounds__(256)
void bucket_sort_kernel(const unsigned* __restrict__ tmpG, const unsigned long long* __restrict__ tmpP,
                        const int* __restrict__ bucketCntG, const int* __restrict__ bucketCntP,
                        int* __restrict__ count, int* __restrict__ offs,
                        int* __restrict__ nbr, unsigned long long* __restrict__ pairs,
                        int N, int Npad, int NBUK) {
    __shared__ int h[256], loffs[256], lcur[256];
    int t = threadIdx.x;
    bool isG = (int)blockIdx.x < NBUK;
    int b = isG ? blockIdx.x : blockIdx.x - NBUK;
    int s = b * BCAP;
    int c = isG ? bucketCntG[b] : bucketCntP[b];
    h[t] = 0;
    __syncthreads();
    if (isG) {
        for (int i = t; i < c; i += 256) atomicAdd(&h[tmpG[s + i] & 255], 1);
    } else {
        for (int i = t; i < c; i += 256) atomicAdd(&h[(int)(tmpP[s + i] >> 56)], 1);
    }
    __syncthreads();
    int v = h[t];
    loffs[t] = v;
    __syncthreads();
    for (int d = 1; d < 256; d <<= 1) {
        int u = (t >= d) ? loffs[t - d] : 0;
        __syncthreads(); loffs[t] += u; __syncthreads();
    }
    int excl = loffs[t] - v;
    lcur[t] = excl;
    int node = b * 256 + t;
    if (node < N) {
        int base = isG ? 0 : Npad;
        count[base + node] = v;
        offs[base + node] = s + excl;
    }
    __syncthreads();
    if (isG) {
        for (int i = t; i < c; i += 256) {
            unsigned w = tmpG[s + i];
            int p = atomicAdd(&lcur[w & 255], 1);
            nbr[s + p] = (int)(w >> 8);
        }
    } else {
        for (int i = t; i < c; i += 256) {
            unsigned long long w = tmpP[s + i];
            int p = atomicAdd(&lcur[(int)(w >> 56)], 1);
            pairs[s + p] = w & 0x00FFFFFFFFFFFFFFull;
        }
    }
}

// ================= agg1: fp8 gather-mean, 8-lane/16B groups (decode-proven layout) =================
// 8 groups of 8 lanes per wave; each lane covers 16 channels (uint4). Row-load
// instruction count halved vs round-9's 16-lane/8B layout.
__global__ void agg1_kernel(const unsigned char* __restrict__ x8, const int* __restrict__ nbr,
                            const int* __restrict__ offs, const int* __restrict__ count,
                            ushort* __restrict__ agg, int N) {
    int w = blockIdx.x * 4 + (threadIdx.x >> 6);
    if (w >= N) return;
    int lane = threadIdx.x & 63;
    int g = lane >> 3, gl = lane & 7;
    int start = offs[w], cnt = count[w];
    float a0[16], a1[16];
#pragma unroll
    for (int i = 0; i < 16; i++) { a0[i] = 0.0f; a1[i] = 0.0f; }
    int j = g;
    for (; j + 8 < cnt; j += 16) {
        int s0 = nbr[start + j];
        int s1 = nbr[start + j + 8];
        uint4 v0 = *(const uint4*)(x8 + (size_t)s0 * IN_CH + gl * 16);
        uint4 v1 = *(const uint4*)(x8 + (size_t)s1 * IN_CH + gl * 16);
        float f0[16], f1[16];
        fp8x16_to_f32(v0, f0); fp8x16_to_f32(v1, f1);
#pragma unroll
        for (int i = 0; i < 16; i++) { a0[i] += f0[i]; a1[i] += f1[i]; }
    }
    if (j < cnt) {
        int s0 = nbr[start + j];
        uint4 v0 = *(const uint4*)(x8 + (size_t)s0 * IN_CH + gl * 16);
        float f0[16];
        fp8x16_to_f32(v0, f0);
#pragma unroll
        for (int i = 0; i < 16; i++) a0[i] += f0[i];
    }
#pragma unroll
    for (int i = 0; i < 16; i++) {
        a0[i] += a1[i];
        a0[i] += __shfl_xor(a0[i], 8, 64);
        a0[i] += __shfl_xor(a0[i], 16, 64);
        a0[i] += __shfl_xor(a0[i], 32, 64);
    }
    if (g == 0) {
        float r = 1.0f / fmaxf((float)cnt, 1.0f);
        ushort8 o0, o1;
#pragma unroll
        for (int i = 0; i < 8; i++) { o0[i] = f2b(a0[i] * r); o1[i] = f2b(a0[i + 8] * r); }
        *(ushort8*)(agg + (size_t)w * IN_CH + gl * 16) = o0;
        *(ushort8*)(agg + (size_t)w * IN_CH + gl * 16 + 8) = o1;
    }
}

// ================= agg2: fp8 gather-mean, 16-lane/16B groups (decode-proven layout) =================
// 4 groups of 16 lanes per wave, depth 2 per group (8 rows in flight/wave).
__global__ void agg2_kernel(const unsigned char* __restrict__ h8, const int* __restrict__ nbr,
                            const int* __restrict__ offs, const int* __restrict__ count,
                            ushort* __restrict__ agg, int N) {
    int w = blockIdx.x * 4 + (threadIdx.x >> 6);
    if (w >= N) return;
    int lane = threadIdx.x & 63;
    int g = lane >> 4, gl = lane & 15;
    int start = offs[w], cnt = count[w];
    float a0[16], a1[16];
#pragma unroll
    for (int i = 0; i < 16; i++) { a0[i] = 0.0f; a1[i] = 0.0f; }
    int j = g;
    for (; j + 4 < cnt; j += 8) {
        int s0 = nbr[start + j];
        int s1 = nbr[start + j + 4];
        uint4 v0 = *(const uint4*)(h8 + (size_t)s0 * HID + gl * 16);
        uint4 v1 = *(const uint4*)(h8 + (size_t)s1 * HID + gl * 16);
        float f0[16], f1[16];
        fp8x16_to_f32(v0, f0); fp8x16_to_f32(v1, f1);
#pragma unroll
        for (int i = 0; i < 16; i++) { a0[i] += f0[i]; a1[i] += f1[i]; }
    }
    if (j < cnt) {
        int s0 = nbr[start + j];
        uint4 v0 = *(const uint4*)(h8 + (size_t)s0 * HID + gl * 16);
        float f0[16];
        fp8x16_to_f32(v0, f0);
#pragma unroll
        for (int i = 0; i < 16; i++) a0[i] += f0[i];
    }
#pragma unroll
    for (int i = 0; i < 16; i++) {
        a0[i] += a1[i];
        a0[i] += __shfl_xor(a0[i], 16, 64);
        a0[i] += __shfl_xor(a0[i], 32, 64);
    }
    if (g == 0) {
        float r = 1.0f / fmaxf((float)cnt, 1.0f);
        ushort8 o0, o1;
#pragma unroll
        for (int i = 0; i < 8; i++) { o0[i] = f2b(a0[i] * r); o1[i] = f2b(a0[i + 8] * r); }
        *(ushort8*)(agg + (size_t)w * HID + gl * 16) = o0;
        *(ushort8*)(agg + (size_t)w * HID + gl * 16 + 8) = o1;
    }
}

// ================= MFMA GEMM: 128-row tile, double-buffered LDS (round-8 proven) =================
template<int KTOT, bool RELU, bool WBF16, bool WFP8>
__global__ __launch_bounds__(512, 4)
void sage_gemm_mfma(const ushort* __restrict__ Aleft, const ushort* __restrict__ Aright,
                    const ushort* __restrict__ Wt, const float* __restrict__ bias,
                    ushort* __restrict__ out, unsigned char* __restrict__ out8, int N) {
    constexpr int KH = KTOT / 2;
    constexpr int S  = KTOT / 32;
    __shared__ ushort smem[2 * 4096 + 2 * 8192];   // As0|As1|Bs0|Bs1 (48 KB)
    ushort* AsB[2] = { smem, smem + 4096 };
    ushort* BsB[2] = { smem + 8192, smem + 16384 };

    const int t = threadIdx.x;                 // 0..511
    const int wave = t >> 6;                   // 0..7
    const int lane = t & 63;
    const int quad = lane >> 4;
    const int l16  = lane & 15;
    const int rowBase = blockIdx.x * 128;

    const int aRow = t >> 2;
    const int aCh  = t & 3;
    const bool aRowOK = (rowBase + aRow) < N;
    const int aLds = ((aRow >> 4) * 64 + (aRow & 15) * 4 + aCh) * 8;

    const int bN   = t >> 1;
    const int bCh0 = (t & 1) * 2;
    const int bFragBase = (bN >> 6) * 256 + ((bN >> 4) & 3) * 64 + (bN & 15) * 4;

    int bFrag[2];
#pragma unroll
    for (int nt = 0; nt < 2; nt++) {
        int c = wave * 32 + nt * 16 + l16;
        bFrag[nt] = ((c >> 6) * 256 + ((c >> 4) & 3) * 64 + (c & 15) * 4 + quad) * 8;
    }

    f32x4 acc[8][2];
#pragma unroll
    for (int i = 0; i < 8; i++)
#pragma unroll
        for (int j = 0; j < 2; j++) acc[i][j] = (f32x4)0.0f;

    ulonglong2 aReg = {0ull, 0ull};
    ulonglong2 bReg[2];

    if (aRowOK)
        aReg = *(const ulonglong2*)(Aleft + (size_t)(rowBase + aRow) * KH + aCh * 8);
    bReg[0] = *(const ulonglong2*)(Wt + (size_t)bN * KTOT + bCh0 * 8);
    bReg[1] = *(const ulonglong2*)(Wt + (size_t)bN * KTOT + (bCh0 + 1) * 8);
    *(ulonglong2*)&AsB[0][aLds] = aReg;
    *(ulonglong2*)&BsB[0][(bFragBase + bCh0) * 8]     = bReg[0];
    *(ulonglong2*)&BsB[0][(bFragBase + bCh0 + 1) * 8] = bReg[1];

#pragma unroll
    for (int s = 0; s < S; s++) {
        __syncthreads();
        const int kn = (s + 1) * 32;
        if (kn < KTOT) {
            if (aRowOK) {
                const ushort* Ap = (kn < KH)
                    ? (Aleft  + (size_t)(rowBase + aRow) * KH + (kn + aCh * 8))
                    : (Aright + (size_t)(rowBase + aRow) * KH + (kn - KH + aCh * 8));
                aReg = *(const ulonglong2*)Ap;
            }
            bReg[0] = *(const ulonglong2*)(Wt + (size_t)bN * KTOT + kn + bCh0 * 8);
            bReg[1] = *(const ulonglong2*)(Wt + (size_t)bN * KTOT + kn + (bCh0 + 1) * 8);
        }

        const ushort* As = AsB[s & 1];
        const ushort* Bs = BsB[s & 1];
        bf16x8 bf[2];
        bf[0] = *(const bf16x8*)&Bs[bFrag[0]];
        bf[1] = *(const bf16x8*)&Bs[bFrag[1]];
#pragma unroll
        for (int mt = 0; mt < 8; mt++) {
            bf16x8 af = *(const bf16x8*)&As[(mt * 64 + l16 * 4 + quad) * 8];
            acc[mt][0] = __builtin_amdgcn_mfma_f32_16x16x32_bf16(af, bf[0], acc[mt][0], 0, 0, 0);
            acc[mt][1] = __builtin_amdgcn_mfma_f32_16x16x32_bf16(af, bf[1], acc[mt][1], 0, 0, 0);
        }

        if (kn < KTOT) {
            ushort* An = AsB[(s + 1) & 1];
            ushort* Bn = BsB[(s + 1) & 1];
            *(ulonglong2*)&An[aLds] = aReg;
            *(ulonglong2*)&Bn[(bFragBase + bCh0) * 8]     = bReg[0];
            *(ulonglong2*)&Bn[(bFragBase + bCh0 + 1) * 8] = bReg[1];
        }
    }

    float bv[2];
#pragma unroll
    for (int nt = 0; nt < 2; nt++) bv[nt] = bias[wave * 32 + nt * 16 + l16];
    ushort* tile = smem;                       // 32 x 256 shorts = 16 KB

#pragma unroll
    for (int hf = 0; hf < 4; hf++) {
        __syncthreads();
#pragma unroll
        for (int mh = 0; mh < 2; mh++) {
            int mt = hf * 2 + mh;
#pragma unroll
            for (int reg = 0; reg < 4; reg++) {
                int rl = mh * 16 + quad * 4 + reg;
                float v0 = acc[mt][0][reg] + bv[0];
                float v1 = acc[mt][1][reg] + bv[1];
                if (RELU) { v0 = fmaxf(v0, 0.0f); v1 = fmaxf(v1, 0.0f); }
                ushort2 o;
                o.x = f2b(v0); o.y = f2b(v1);
                *(ushort2*)&tile[rl * 256 + (wave >> 1) * 64 + l16 * 4 + (wave & 1) * 2] = o;
            }
        }
        __syncthreads();
#pragma unroll
        for (int i = 0; i < 2; i++) {
            int ch = i * 512 + t;
            int rl = ch >> 5, c16 = ch & 31;
            int row = rowBase + hf * 32 + rl;
            if (row < N) {
                ushort8 w = *(const ushort8*)&tile[rl * 256 + c16 * 8];
                if (WBF16)
                    *(ushort8*)(out + (size_t)row * 256 + c16 * 8) = w;
                if (WFP8) {
                    int u0 = __builtin_amdgcn_cvt_pk_fp8_f32(b2f(w[0]), b2f(w[1]), 0, false);
                    u0 = __builtin_amdgcn_cvt_pk_fp8_f32(b2f(w[2]), b2f(w[3]), u0, true);
                    int u1 = __builtin_amdgcn_cvt_pk_fp8_f32(b2f(w[4]), b2f(w[5]), 0, false);
                    u1 = __builtin_amdgcn_cvt_pk_fp8_f32(b2f(w[6]), b2f(w[7]), u1, true);
                    uint2 o8;
                    o8.x = (unsigned)u0; o8.y = (unsigned)u1;
                    *(uint2*)(out8 + (size_t)row * 256 + c16 * 8) = o8;
                }
            }
        }
    }
}

// ================= decode: 16-lane/16B groups, 2 dots per group-iter (round-9 proven) =================
__global__ void decode2_kernel(const unsigned char* __restrict__ z8,
                               const unsigned long long* __restrict__ pairs,
                               const int* __restrict__ offsA, const int* __restrict__ countA,
                               float* __restrict__ out, int N) {
    int a = blockIdx.x * 4 + (threadIdx.x >> 6);
    if (a >= N) return;
    int cnt = countA[a];
    if (cnt == 0) return;
    int lane = threadIdx.x & 63;
    int g = lane >> 4, gl = lane & 15;
    int start = offsA[a];

    float ar[16];
    {
        uint4 va = *(const uint4*)(z8 + (size_t)a * HID + gl * 16);
        fp8x16_to_f32(va, ar);
    }

    int j = g;
    for (; j + 4 < cnt; j += 8) {              // depth 2 per group: j, j+4
        unsigned long long p0 = pairs[start + j];
        unsigned long long p1 = pairs[start + j + 4];
        int b0 = (int)((p0 >> 32) & 0xFFFFFFu), e0 = (int)(p0 & 0xffffffffu);
        int b1 = (int)((p1 >> 32) & 0xFFFFFFu), e1 = (int)(p1 & 0xffffffffu);
        uint4 v0 = *(const uint4*)(z8 + (size_t)b0 * HID + gl * 16);
        uint4 v1 = *(const uint4*)(z8 + (size_t)b1 * HID + gl * 16);
        float f0[16], f1[16];
        fp8x16_to_f32(v0, f0);
        fp8x16_to_f32(v1, f1);
        float s0a = 0.f, s0b = 0.f, s1a = 0.f, s1b = 0.f;
#pragma unroll
        for (int i = 0; i < 8; i++) {
            s0a = fmaf(ar[i], f0[i], s0a);
            s0b = fmaf(ar[i + 8], f0[i + 8], s0b);
            s1a = fmaf(ar[i], f1[i], s1a);
            s1b = fmaf(ar[i + 8], f1[i + 8], s1b);
        }
        float s0 = s0a + s0b, s1 = s1a + s1b;
#pragma unroll
        for (int off = 1; off < 16; off <<= 1) {
            s0 += __shfl_xor(s0, off, 64);
            s1 += __shfl_xor(s1, off, 64);
        }
        if (gl == 0) { out[e0] = s0; out[e1] = s1; }
    }
    for (; j < cnt; j += 4) {
        unsigned long long p0 = pairs[start + j];
        int b0 = (int)((p0 >> 32) & 0xFFFFFFu), e0 = (int)(p0 & 0xffffffffu);
        uint4 v0 = *(const uint4*)(z8 + (size_t)b0 * HID + gl * 16);
        float f0[16];
        fp8x16_to_f32(v0, f0);
        float s0a = 0.f, s0b = 0.f;
#pragma unroll
        for (int i = 0; i < 8; i++) {
            s0a = fmaf(ar[i], f0[i], s0a);
            s0b = fmaf(ar[i + 8], f0[i + 8], s0b);
        }
        float s0 = s0a + s0b;
#pragma unroll
        for (int off = 1; off < 16; off <<= 1) s0 += __shfl_xor(s0, off, 64);
        if (gl == 0) out[e0] = s0;
    }
}

extern "C" void kernel_launch(void* const* d_in, const int* in_sizes, int n_in,
                              void* d_out, int out_size, void* d_ws, size_t ws_size,
                              hipStream_t stream) {
    const float* x    = (const float*)d_in[0];
    const int* eidx   = (const int*)d_in[1];
    const int* edges  = (const int*)d_in[2];
    const float* W1l  = (const float*)d_in[3];
    const float* b1   = (const float*)d_in[4];
    const float* W1r  = (const float*)d_in[5];
    const float* W2l  = (const float*)d_in[6];
    const float* b2   = (const float*)d_in[7];
    const float* W2r  = (const float*)d_in[8];
    float* out = (float*)d_out;

    const int N  = in_sizes[0] / IN_CH;
    const int E  = in_sizes[1] / 2;
    const int E2 = in_sizes[2] / 2;
    const int* src = eidx;
    const int* dst = eidx + E;

    const int NBUK = (N + 255) >> 8;            // 256-node buckets (<=512)
    const int Npad = NBUK << 8;
    const int NBG  = (E  + 256 * PB_VT - 1) / (256 * PB_VT);
    const int NBP  = (E2 + 256 * PB_VT - 1) / (256 * PB_VT);

    int* count      = (int*)d_ws;
    int* offs       = count + 2 * Npad;
    int* bucketCntG = offs + 2 * Npad;
    int* bucketCntP = bucketCntG + 512;
    int* nbr        = bucketCntP + 512;          // padded: NBUK*BCAP ints
    size_t intWords = (size_t)(nbr - (int*)d_ws) + (size_t)NBUK * BCAP;
    intWords = (intWords + 1) & ~(size_t)1;
    unsigned long long* pairs = (unsigned long long*)((int*)d_ws + intWords); // NBUK*BCAP
    ushort* xb    = (ushort*)(pairs + (size_t)NBUK * BCAP);
    ushort* agg1b = xb + (size_t)N * IN_CH;
    ushort* agg2b = xb;                          // overlay after gemm1
    ushort* h     = agg1b + (size_t)N * IN_CH;   // bf16 (gemm2 Aright, accurate)
    unsigned char* h8 = (unsigned char*)(h + (size_t)N * HID);   // fp8 copy for agg2 gather
    unsigned char* z8 = h8 + (size_t)N * HID;                    // fp8 z (decode only)
    ushort* Wt1   = (ushort*)(z8 + (size_t)N * HID);
    ushort* Wt2   = Wt1 + 256 * 256;
    // x8 (fp8 copy of x for agg1 gather) overlays z8's SECOND HALF:
    //   lifetime cvt->agg1; z8 written only by gemm2 (after agg1). tmp arrays
    //   (below) only reach 3.2 MB into z8's first half -> no overlap.
    unsigned char* x8 = z8 + (size_t)N * HID / 2;
    // padded tmp partition arrays overlay h8 + z8 first half (dead until gemm1/gemm2)
    unsigned* tmpG = (unsigned*)h8;              // NBUK*BCAP uints
    unsigned long long* tmpP =
        (unsigned long long*)(tmpG + (((size_t)NBUK * BCAP + 1) & ~(size_t)1));

    // ---- fused conversions (bf16 + fp8 x8) + counter zeroing (1 launch) ----
    int n4 = N * IN_CH / 4;
    int nCvt = (n4 + 255) / 256;
    fused_cvt_prep<<<nCvt + 256 + 512 + 1, 256, 0, stream>>>(
        x, xb, x8, n4, nCvt, W1l, W1r, Wt1, W2l, W2r, Wt2, bucketCntG, bucketCntP);

    // ---- 2-kernel sort: reservation scatter + per-bucket sort ----
    scatter_reserve_kernel<<<NBG + NBP, 256, 0, stream>>>(
        src, dst, edges, bucketCntG, bucketCntP, tmpG, tmpP, E, E2, NBUK, NBG);
    bucket_sort_kernel<<<2 * NBUK, 256, 0, stream>>>(
        tmpG, tmpP, bucketCntG, bucketCntP, count, offs, nbr, pairs, N, Npad, NBUK);

    // ---- layer 1: agg (fp8 gather) + GEMM (writes h bf16 AND h8 fp8) ----
    agg1_kernel<<<(N + 3) / 4, 256, 0, stream>>>(x8, nbr, offs, count, agg1b, N);
    sage_gemm_mfma<2 * IN_CH, true, true, true><<<(N + 127) / 128, 512, 0, stream>>>(
        agg1b, xb, Wt1, b1, h, h8, N);

    // ---- layer 2: agg (fp8 gather) + GEMM (writes z8 fp8 only) ----
    agg2_kernel<<<(N + 3) / 4, 256, 0, stream>>>(h8, nbr, offs, count, agg2b, N);
    sage_gemm_mfma<2 * HID, false, false, true><<<(N + 127) / 128, 512, 0, stream>>>(
        agg2b, h, Wt2, b2, h /*unused*/, z8, N);

    // ---- decode (fp8 z) ----
    decode2_kernel<<<(N + 3) / 4, 256, 0, stream>>>(z8, pairs, offs + Npad, count + Npad, out, N);
}

// Round 11
// 478.147 us; speedup vs baseline: 1.0392x; 1.0392x over previous
//
#include <hip/hip_runtime.h>

#define IN_CH 128
#define HID   256
#define PB_VT 16            // 4096 edges per partition block
#define BCAP  6144          // per-bucket capacity (mean 4096, sd 64 -> +32 sd)

typedef __attribute__((ext_vector_type(8))) short bf16x8;
typedef __attribute__((ext_vector_type(4))) float f32x4;
typedef __attribute__((ext_vector_type(2))) float f32x2;
typedef __attribute__((ext_vector_type(8))) unsigned short ushort8;

__device__ __forceinline__ ushort f2b(float f) {
    unsigned u = __float_as_uint(f);
    unsigned r = (u + 0x7fffu + ((u >> 16) & 1u)) >> 16;
    return (ushort)r;
}
__device__ __forceinline__ float b2f(ushort h) {
    return __uint_as_float(((unsigned)h) << 16);
}
// 8 packed fp8 (e4m3, HW cvt) -> 8 f32
__device__ __forceinline__ void fp8x8_to_f32(uint2 v, float f[8]) {
    f32x2 a = __builtin_amdgcn_cvt_pk_f32_fp8((int)v.x, false);
    f32x2 b = __builtin_amdgcn_cvt_pk_f32_fp8((int)v.x, true);
    f32x2 c = __builtin_amdgcn_cvt_pk_f32_fp8((int)v.y, false);
    f32x2 d = __builtin_amdgcn_cvt_pk_f32_fp8((int)v.y, true);
    f[0] = a[0]; f[1] = a[1]; f[2] = b[0]; f[3] = b[1];
    f[4] = c[0]; f[5] = c[1]; f[6] = d[0]; f[7] = d[1];
}
// 16 packed fp8 -> 16 f32
__device__ __forceinline__ void fp8x16_to_f32(uint4 v, float f[16]) {
    uint2 lo; lo.x = v.x; lo.y = v.y;
    uint2 hi; hi.x = v.z; hi.y = v.w;
    fp8x8_to_f32(lo, f);
    fp8x8_to_f32(hi, f + 8);
}

// ================= fused bf16+fp8 conversions + counter zeroing (round-5 proven) =================
__device__ __forceinline__ void prep_w_body(const float* __restrict__ Wl,
                                            const float* __restrict__ Wr,
                                            ushort* __restrict__ Wt,
                                            int KH, bool permK, int idx) {
    int ktot = 2 * KH;
    if (idx >= 256 * ktot) return;
    int n = idx / ktot, k = idx % ktot;
    int kh = (k < KH) ? k : (k - KH);
    int c = kh;
    if (permK) {
        int j = kh & 63;
        c = (kh & ~63) | ((j & 3) * 16 + (j >> 2));
    }
    float v = (k < KH) ? Wl[(size_t)c * 256 + n] : Wr[(size_t)c * 256 + n];
    Wt[idx] = f2b(v);
}

__global__ __launch_bounds__(256)
void fused_cvt_prep(const float* __restrict__ x, ushort* __restrict__ xb,
                    unsigned char* __restrict__ x8, int n4, int nCvt,
                    const float* __restrict__ W1l, const float* __restrict__ W1r, ushort* __restrict__ Wt1,
                    const float* __restrict__ W2l, const float* __restrict__ W2r, ushort* __restrict__ Wt2,
                    int* __restrict__ bucketCntG, int* __restrict__ bucketCntP) {
    int b = blockIdx.x;
    int t = threadIdx.x;
    if (b < nCvt) {
        int i = b * 256 + t;
        if (i < n4) {
            float4 v = ((const float4*)x)[i];
            ushort4 u;
            u.x = f2b(v.x); u.y = f2b(v.y); u.z = f2b(v.z); u.w = f2b(v.w);
            ((ushort4*)xb)[i] = u;
            int p = __builtin_amdgcn_cvt_pk_fp8_f32(v.x, v.y, 0, false);
            p = __builtin_amdgcn_cvt_pk_fp8_f32(v.z, v.w, p, true);
            ((unsigned*)x8)[i] = (unsigned)p;
        }
    } else if (b < nCvt + 256) {
        prep_w_body(W1l, W1r, Wt1, IN_CH, false, (b - nCvt) * 256 + t);
    } else if (b < nCvt + 256 + 512) {
        prep_w_body(W2l, W2r, Wt2, HID, true, (b - nCvt - 256) * 256 + t);
    } else {
        bucketCntG[t] = 0;
        bucketCntG[t + 256] = 0;
        bucketCntP[t] = 0;
        bucketCntP[t + 256] = 0;
    }
}

// ================= single-pass reservation scatter (round-4/5 proven) =================
__global__ __launch_bounds__(256)
void scatter_reserve_kernel(const int* __restrict__ src, const int* __restrict__ dst,
                            const int* __restrict__ edges,
                            int* __restrict__ bucketCntG, int* __restrict__ bucketCntP,
                            unsigned* __restrict__ tmpG, unsigned long long* __restrict__ tmpP,
                            int E, int E2, int NBUK, int NBG) {
    __shared__ int hist[512];
    __shared__ int cur[512];
    int t = threadIdx.x;
    bool isG = (int)blockIdx.x < NBG;
    int blk = isG ? blockIdx.x : blockIdx.x - NBG;
    for (int i = t; i < NBUK; i += 256) hist[i] = 0;
    __syncthreads();
    long long e0 = (long long)blk * (256 * PB_VT);
    if (isG) {
#pragma unroll
        for (int i = 0; i < PB_VT; i++) {
            long long e = e0 + i * 256 + t;
            if (e < E) atomicAdd(&hist[dst[e] >> 8], 1);
        }
    } else {
#pragma unroll
        for (int i = 0; i < PB_VT; i++) {
            long long e = e0 + i * 256 + t;
            if (e < E2) atomicAdd(&hist[edges[e * 2] >> 8], 1);
        }
    }
    __syncthreads();
    int* bcnt = isG ? bucketCntG : bucketCntP;
    for (int i = t; i < NBUK; i += 256) {
        int hc = hist[i];
        cur[i] = (hc > 0) ? atomicAdd(&bcnt[i], hc) : 0;
    }
    __syncthreads();
    if (isG) {
#pragma unroll
        for (int i = 0; i < PB_VT; i++) {
            long long e = e0 + i * 256 + t;
            if (e < E) {
                int d = dst[e];
                int bk = d >> 8;
                int pos = atomicAdd(&cur[bk], 1);       // LDS atomic
                tmpG[(size_t)bk * BCAP + pos] = ((unsigned)src[e] << 8) | (unsigned)(d & 255);
            }
        }
    } else {
#pragma unroll
        for (int i = 0; i < PB_VT; i++) {
            long long e = e0 + i * 256 + t;
            if (e < E2) {
                int2 ab = *(const int2*)(edges + e * 2);
                int bk = ab.x >> 8;
                int pos = atomicAdd(&cur[bk], 1);
                tmpP[(size_t)bk * BCAP + pos] = ((unsigned long long)(unsigned)(ab.x & 255) << 56)
                                              | ((unsigned long long)(unsigned)ab.y << 32)
                                              | (unsigned)e;
            }
        }
    }
}

// ================= per-bucket sort into padded per-node lists (round-4 proven) =================
__global__ __launch_bounds__(256)
void bucket_sort_kernel(const unsigned* __restrict__ tmpG, const unsigned long long* __restrict__ tmpP,
                        const int* __restrict__ bucketCntG, const int* __restrict__ bucketCntP,
                        int* __restrict__ count, int* __restrict__ offs,
                        int* __restrict__ nbr, unsigned long long* __restrict__ pairs,
                        int N, int Npad, int NBUK) {
    __shared__ int h[256], loffs[256], lcur[256];
    int t = threadIdx.x;
    bool isG = (int)blockIdx.x < NBUK;
    int b = isG ? blockIdx.x : blockIdx.x - NBUK;
    int s = b * BCAP;
    int c = isG ? bucketCntG[b] : bucketCntP[b];
    h[t] = 0;
    __syncthreads();
    if (isG) {
        for (int i = t; i < c; i += 256) atomicAdd(&h[tmpG[s + i] & 255], 1);
    } else {
        for (int i = t; i < c; i += 256) atomicAdd(&h[(int)(tmpP[s + i] >> 56)], 1);
    }
    __syncthreads();
    int v = h[t];
    loffs[t] = v;
    __syncthreads();
    for (int d = 1; d < 256; d <<= 1) {
        int u = (t >= d) ? loffs[t - d] : 0;
        __syncthreads(); loffs[t] += u; __syncthreads();
    }
    int excl = loffs[t] - v;
    lcur[t] = excl;
    int node = b * 256 + t;
    if (node < N) {
        int base = isG ? 0 : Npad;
        count[base + node] = v;
        offs[base + node] = s + excl;
    }
    __syncthreads();
    if (isG) {
        for (int i = t; i < c; i += 256) {
            unsigned w = tmpG[s + i];
            int p = atomicAdd(&lcur[w & 255], 1);
            nbr[s + p] = (int)(w >> 8);
        }
    } else {
        for (int i = t; i < c; i += 256) {
            unsigned long long w = tmpP[s + i];
            int p = atomicAdd(&lcur[(int)(w >> 56)], 1);
            pairs[s + p] = w & 0x00FFFFFFFFFFFFFFull;
        }
    }
}

// ================= agg1: fp8 gather-mean, 16-lane/8B groups (round-9 proven) =================
__global__ void agg1_kernel(const unsigned char* __restrict__ x8, const int* __restrict__ nbr,
                            const int* __restrict__ offs, const int* __restrict__ count,
                            ushort* __restrict__ agg, int N) {
    int w = blockIdx.x * 4 + (threadIdx.x >> 6);
    if (w >= N) return;
    int lane = threadIdx.x & 63;
    int grp = lane >> 4, gl = lane & 15;
    int start = offs[w], cnt = count[w];
    float a0[8], a1[8];
#pragma unroll
    for (int i = 0; i < 8; i++) { a0[i] = 0.0f; a1[i] = 0.0f; }
    int j = grp;
    for (; j + 4 < cnt; j += 8) {
        int s0 = nbr[start + j];
        int s1 = nbr[start + j + 4];
        uint2 v0 = *(const uint2*)(x8 + (size_t)s0 * IN_CH + gl * 8);
        uint2 v1 = *(const uint2*)(x8 + (size_t)s1 * IN_CH + gl * 8);
        float f0[8], f1[8];
        fp8x8_to_f32(v0, f0); fp8x8_to_f32(v1, f1);
#pragma unroll
        for (int i = 0; i < 8; i++) { a0[i] += f0[i]; a1[i] += f1[i]; }
    }
    if (j < cnt) {
        int s0 = nbr[start + j];
        uint2 v0 = *(const uint2*)(x8 + (size_t)s0 * IN_CH + gl * 8);
        float f0[8];
        fp8x8_to_f32(v0, f0);
#pragma unroll
        for (int i = 0; i < 8; i++) a0[i] += f0[i];
    }
#pragma unroll
    for (int i = 0; i < 8; i++) {
        a0[i] += a1[i];
        a0[i] += __shfl_xor(a0[i], 16, 64);
        a0[i] += __shfl_xor(a0[i], 32, 64);
    }
    if (grp == 0) {
        float r = 1.0f / fmaxf((float)cnt, 1.0f);
        ushort8 o;
#pragma unroll
        for (int i = 0; i < 8; i++) o[i] = f2b(a0[i] * r);
        *(ushort8*)(agg + (size_t)w * IN_CH + gl * 8) = o;
    }
}

// ================= agg2: fp8 gather-mean, 32-lane/8B halves (round-5/9 proven) =================
__global__ void agg2_kernel(const unsigned char* __restrict__ h8, const int* __restrict__ nbr,
                            const int* __restrict__ offs, const int* __restrict__ count,
                            ushort* __restrict__ agg, int N) {
    int w = blockIdx.x * 4 + (threadIdx.x >> 6);
    if (w >= N) return;
    int lane = threadIdx.x & 63;
    int half = lane >> 5, hl = lane & 31;
    int start = offs[w], cnt = count[w];
    float a0[8], a1[8];
#pragma unroll
    for (int i = 0; i < 8; i++) { a0[i] = 0.0f; a1[i] = 0.0f; }
    int j = half;
    for (; j + 6 < cnt; j += 8) {
        int s0 = nbr[start + j];
        int s1 = nbr[start + j + 2];
        int s2 = nbr[start + j + 4];
        int s3 = nbr[start + j + 6];
        uint2 v0 = *(const uint2*)(h8 + (size_t)s0 * HID + hl * 8);
        uint2 v1 = *(const uint2*)(h8 + (size_t)s1 * HID + hl * 8);
        uint2 v2 = *(const uint2*)(h8 + (size_t)s2 * HID + hl * 8);
        uint2 v3 = *(const uint2*)(h8 + (size_t)s3 * HID + hl * 8);
        float f0[8], f1[8], f2[8], f3[8];
        fp8x8_to_f32(v0, f0); fp8x8_to_f32(v1, f1);
        fp8x8_to_f32(v2, f2); fp8x8_to_f32(v3, f3);
#pragma unroll
        for (int i = 0; i < 8; i++) {
            a0[i] += f0[i] + f2[i];
            a1[i] += f1[i] + f3[i];
        }
    }
    for (; j < cnt; j += 2) {
        int s0 = nbr[start + j];
        uint2 v0 = *(const uint2*)(h8 + (size_t)s0 * HID + hl * 8);
        float f0[8];
        fp8x8_to_f32(v0, f0);
#pragma unroll
        for (int i = 0; i < 8; i++) a0[i] += f0[i];
    }
#pragma unroll
    for (int i = 0; i < 8; i++) {
        a0[i] += a1[i];
        a0[i] += __shfl_xor(a0[i], 32, 64);
    }
    if (half == 0) {
        float r = 1.0f / fmaxf((float)cnt, 1.0f);
        ushort8 o;
#pragma unroll
        for (int i = 0; i < 8; i++) o[i] = f2b(a0[i] * r);
        *(ushort8*)(agg + (size_t)w * HID + hl * 8) = o;
    }
}

// ================= MFMA GEMM: 128-row tile, double-buffered LDS (round-8 proven) =================
template<int KTOT, bool RELU, bool WBF16, bool WFP8>
__global__ __launch_bounds__(512, 4)
void sage_gemm_mfma(const ushort* __restrict__ Aleft, const ushort* __restrict__ Aright,
                    const ushort* __restrict__ Wt, const float* __restrict__ bias,
                    ushort* __restrict__ out, unsigned char* __restrict__ out8, int N) {
    constexpr int KH = KTOT / 2;
    constexpr int S  = KTOT / 32;
    __shared__ ushort smem[2 * 4096 + 2 * 8192];   // As0|As1|Bs0|Bs1 (48 KB)
    ushort* AsB[2] = { smem, smem + 4096 };
    ushort* BsB[2] = { smem + 8192, smem + 16384 };

    const int t = threadIdx.x;                 // 0..511
    const int wave = t >> 6;                   // 0..7
    const int lane = t & 63;
    const int quad = lane >> 4;
    const int l16  = lane & 15;
    const int rowBase = blockIdx.x * 128;

    const int aRow = t >> 2;
    const int aCh  = t & 3;
    const bool aRowOK = (rowBase + aRow) < N;
    const int aLds = ((aRow >> 4) * 64 + (aRow & 15) * 4 + aCh) * 8;

    const int bN   = t >> 1;
    const int bCh0 = (t & 1) * 2;
    const int bFragBase = (bN >> 6) * 256 + ((bN >> 4) & 3) * 64 + (bN & 15) * 4;

    int bFrag[2];
#pragma unroll
    for (int nt = 0; nt < 2; nt++) {
        int c = wave * 32 + nt * 16 + l16;
        bFrag[nt] = ((c >> 6) * 256 + ((c >> 4) & 3) * 64 + (c & 15) * 4 + quad) * 8;
    }

    f32x4 acc[8][2];
#pragma unroll
    for (int i = 0; i < 8; i++)
#pragma unroll
        for (int j = 0; j < 2; j++) acc[i][j] = (f32x4)0.0f;

    ulonglong2 aReg = {0ull, 0ull};
    ulonglong2 bReg[2];

    if (aRowOK)
        aReg = *(const ulonglong2*)(Aleft + (size_t)(rowBase + aRow) * KH + aCh * 8);
    bReg[0] = *(const ulonglong2*)(Wt + (size_t)bN * KTOT + bCh0 * 8);
    bReg[1] = *(const ulonglong2*)(Wt + (size_t)bN * KTOT + (bCh0 + 1) * 8);
    *(ulonglong2*)&AsB[0][aLds] = aReg;
    *(ulonglong2*)&BsB[0][(bFragBase + bCh0) * 8]     = bReg[0];
    *(ulonglong2*)&BsB[0][(bFragBase + bCh0 + 1) * 8] = bReg[1];

#pragma unroll
    for (int s = 0; s < S; s++) {
        __syncthreads();
        const int kn = (s + 1) * 32;
        if (kn < KTOT) {
            if (aRowOK) {
                const ushort* Ap = (kn < KH)
                    ? (Aleft  + (size_t)(rowBase + aRow) * KH + (kn + aCh * 8))
                    : (Aright + (size_t)(rowBase + aRow) * KH + (kn - KH + aCh * 8));
                aReg = *(const ulonglong2*)Ap;
            }
            bReg[0] = *(const ulonglong2*)(Wt + (size_t)bN * KTOT + kn + bCh0 * 8);
            bReg[1] = *(const ulonglong2*)(Wt + (size_t)bN * KTOT + kn + (bCh0 + 1) * 8);
        }

        const ushort* As = AsB[s & 1];
        const ushort* Bs = BsB[s & 1];
        bf16x8 bf[2];
        bf[0] = *(const bf16x8*)&Bs[bFrag[0]];
        bf[1] = *(const bf16x8*)&Bs[bFrag[1]];
#pragma unroll
        for (int mt = 0; mt < 8; mt++) {
            bf16x8 af = *(const bf16x8*)&As[(mt * 64 + l16 * 4 + quad) * 8];
            acc[mt][0] = __builtin_amdgcn_mfma_f32_16x16x32_bf16(af, bf[0], acc[mt][0], 0, 0, 0);
            acc[mt][1] = __builtin_amdgcn_mfma_f32_16x16x32_bf16(af, bf[1], acc[mt][1], 0, 0, 0);
        }

        if (kn < KTOT) {
            ushort* An = AsB[(s + 1) & 1];
            ushort* Bn = BsB[(s + 1) & 1];
            *(ulonglong2*)&An[aLds] = aReg;
            *(ulonglong2*)&Bn[(bFragBase + bCh0) * 8]     = bReg[0];
            *(ulonglong2*)&Bn[(bFragBase + bCh0 + 1) * 8] = bReg[1];
        }
    }

    float bv[2];
#pragma unroll
    for (int nt = 0; nt < 2; nt++) bv[nt] = bias[wave * 32 + nt * 16 + l16];
    ushort* tile = smem;                       // 32 x 256 shorts = 16 KB

#pragma unroll
    for (int hf = 0; hf < 4; hf++) {
        __syncthreads();
#pragma unroll
        for (int mh = 0; mh < 2; mh++) {
            int mt = hf * 2 + mh;
#pragma unroll
            for (int reg = 0; reg < 4; reg++) {
                int rl = mh * 16 + quad * 4 + reg;
                float v0 = acc[mt][0][reg] + bv[0];
                float v1 = acc[mt][1][reg] + bv[1];
                if (RELU) { v0 = fmaxf(v0, 0.0f); v1 = fmaxf(v1, 0.0f); }
                ushort2 o;
                o.x = f2b(v0); o.y = f2b(v1);
                *(ushort2*)&tile[rl * 256 + (wave >> 1) * 64 + l16 * 4 + (wave & 1) * 2] = o;
            }
        }
        __syncthreads();
#pragma unroll
        for (int i = 0; i < 2; i++) {
            int ch = i * 512 + t;
            int rl = ch >> 5, c16 = ch & 31;
            int row = rowBase + hf * 32 + rl;
            if (row < N) {
                ushort8 w = *(const ushort8*)&tile[rl * 256 + c16 * 8];
                if (WBF16)
                    *(ushort8*)(out + (size_t)row * 256 + c16 * 8) = w;
                if (WFP8) {
                    int u0 = __builtin_amdgcn_cvt_pk_fp8_f32(b2f(w[0]), b2f(w[1]), 0, false);
                    u0 = __builtin_amdgcn_cvt_pk_fp8_f32(b2f(w[2]), b2f(w[3]), u0, true);
                    int u1 = __builtin_amdgcn_cvt_pk_fp8_f32(b2f(w[4]), b2f(w[5]), 0, false);
                    u1 = __builtin_amdgcn_cvt_pk_fp8_f32(b2f(w[6]), b2f(w[7]), u1, true);
                    uint2 o8;
                    o8.x = (unsigned)u0; o8.y = (unsigned)u1;
                    *(uint2*)(out8 + (size_t)row * 256 + c16 * 8) = o8;
                }
            }
        }
    }
}

// ================= decode: 16-lane/16B groups, 2 dots per group-iter (round-9 proven) =================
__global__ void decode2_kernel(const unsigned char* __restrict__ z8,
                               const unsigned long long* __restrict__ pairs,
                               const int* __restrict__ offsA, const int* __restrict__ countA,
                               float* __restrict__ out, int N) {
    int a = blockIdx.x * 4 + (threadIdx.x >> 6);
    if (a >= N) return;
    int cnt = countA[a];
    if (cnt == 0) return;
    int lane = threadIdx.x & 63;
    int g = lane >> 4, gl = lane & 15;
    int start = offsA[a];

    float ar[16];
    {
        uint4 va = *(const uint4*)(z8 + (size_t)a * HID + gl * 16);
        fp8x16_to_f32(va, ar);
    }

    int j = g;
    for (; j + 4 < cnt; j += 8) {              // depth 2 per group: j, j+4
        unsigned long long p0 = pairs[start + j];
        unsigned long long p1 = pairs[start + j + 4];
        int b0 = (int)((p0 >> 32) & 0xFFFFFFu), e0 = (int)(p0 & 0xffffffffu);
        int b1 = (int)((p1 >> 32) & 0xFFFFFFu), e1 = (int)(p1 & 0xffffffffu);
        uint4 v0 = *(const uint4*)(z8 + (size_t)b0 * HID + gl * 16);
        uint4 v1 = *(const uint4*)(z8 + (size_t)b1 * HID + gl * 16);
        float f0[16], f1[16];
        fp8x16_to_f32(v0, f0);
        fp8x16_to_f32(v1, f1);
        float s0a = 0.f, s0b = 0.f, s1a = 0.f, s1b = 0.f;
#pragma unroll
        for (int i = 0; i < 8; i++) {
            s0a = fmaf(ar[i], f0[i], s0a);
            s0b = fmaf(ar[i + 8], f0[i + 8], s0b);
            s1a = fmaf(ar[i], f1[i], s1a);
            s1b = fmaf(ar[i + 8], f1[i + 8], s1b);
        }
        float s0 = s0a + s0b, s1 = s1a + s1b;
#pragma unroll
        for (int off = 1; off < 16; off <<= 1) {
            s0 += __shfl_xor(s0, off, 64);
            s1 += __shfl_xor(s1, off, 64);
        }
        if (gl == 0) { out[e0] = s0; out[e1] = s1; }
    }
    for (; j < cnt; j += 4) {
        unsigned long long p0 = pairs[start + j];
        int b0 = (int)((p0 >> 32) & 0xFFFFFFu), e0 = (int)(p0 & 0xffffffffu);
        uint4 v0 = *(const uint4*)(z8 + (size_t)b0 * HID + gl * 16);
        float f0[16];
        fp8x16_to_f32(v0, f0);
        float s0a = 0.f, s0b = 0.f;
#pragma unroll
        for (int i = 0; i < 8; i++) {
            s0a = fmaf(ar[i], f0[i], s0a);
            s0b = fmaf(ar[i + 8], f0[i + 8], s0b);
        }
        float s0 = s0a + s0b;
#pragma unroll
        for (int off = 1; off < 16; off <<= 1) s0 += __shfl_xor(s0, off, 64);
        if (gl == 0) out[e0] = s0;
    }
}

extern "C" void kernel_launch(void* const* d_in, const int* in_sizes, int n_in,
                              void* d_out, int out_size, void* d_ws, size_t ws_size,
                              hipStream_t stream) {
    const float* x    = (const float*)d_in[0];
    const int* eidx   = (const int*)d_in[1];
    const int* edges  = (const int*)d_in[2];
    const float* W1l  = (const float*)d_in[3];
    const float* b1   = (const float*)d_in[4];
    const float* W1r  = (const float*)d_in[5];
    const float* W2l  = (const float*)d_in[6];
    const float* b2   = (const float*)d_in[7];
    const float* W2r  = (const float*)d_in[8];
    float* out = (float*)d_out;

    const int N  = in_sizes[0] / IN_CH;
    const int E  = in_sizes[1] / 2;
    const int E2 = in_sizes[2] / 2;
    const int* src = eidx;
    const int* dst = eidx + E;

    const int NBUK = (N + 255) >> 8;            // 256-node buckets (<=512)
    const int Npad = NBUK << 8;
    const int NBG  = (E  + 256 * PB_VT - 1) / (256 * PB_VT);
    const int NBP  = (E2 + 256 * PB_VT - 1) / (256 * PB_VT);

    int* count      = (int*)d_ws;
    int* offs       = count + 2 * Npad;
    int* bucketCntG = offs + 2 * Npad;
    int* bucketCntP = bucketCntG + 512;
    int* nbr        = bucketCntP + 512;          // padded: NBUK*BCAP ints
    size_t intWords = (size_t)(nbr - (int*)d_ws) + (size_t)NBUK * BCAP;
    intWords = (intWords + 1) & ~(size_t)1;
    unsigned long long* pairs = (unsigned long long*)((int*)d_ws + intWords); // NBUK*BCAP
    ushort* xb    = (ushort*)(pairs + (size_t)NBUK * BCAP);
    ushort* agg1b = xb + (size_t)N * IN_CH;
    ushort* agg2b = xb;                          // overlay after gemm1
    ushort* h     = agg1b + (size_t)N * IN_CH;   // bf16 (gemm2 Aright, accurate)
    unsigned char* h8 = (unsigned char*)(h + (size_t)N * HID);   // fp8 copy for agg2 gather
    unsigned char* z8 = h8 + (size_t)N * HID;                    // fp8 z (decode only)
    ushort* Wt1   = (ushort*)(z8 + (size_t)N * HID);
    ushort* Wt2   = Wt1 + 256 * 256;
    // x8 (fp8 copy of x for agg1 gather) overlays z8's SECOND HALF:
    //   lifetime cvt->agg1; z8 written only by gemm2 (after agg1). tmp arrays
    //   (below) only reach 3.2 MB into z8's first half -> no overlap.
    unsigned char* x8 = z8 + (size_t)N * HID / 2;
    // padded tmp partition arrays overlay h8 + z8 first half (dead until gemm1/gemm2)
    unsigned* tmpG = (unsigned*)h8;              // NBUK*BCAP uints
    unsigned long long* tmpP =
        (unsigned long long*)(tmpG + (((size_t)NBUK * BCAP + 1) & ~(size_t)1));

    // ---- fused conversions (bf16 + fp8 x8) + counter zeroing (1 launch) ----
    int n4 = N * IN_CH / 4;
    int nCvt = (n4 + 255) / 256;
    fused_cvt_prep<<<nCvt + 256 + 512 + 1, 256, 0, stream>>>(
        x, xb, x8, n4, nCvt, W1l, W1r, Wt1, W2l, W2r, Wt2, bucketCntG, bucketCntP);

    // ---- 2-kernel sort: reservation scatter + per-bucket sort ----
    scatter_reserve_kernel<<<NBG + NBP, 256, 0, stream>>>(
        src, dst, edges, bucketCntG, bucketCntP, tmpG, tmpP, E, E2, NBUK, NBG);
    bucket_sort_kernel<<<2 * NBUK, 256, 0, stream>>>(
        tmpG, tmpP, bucketCntG, bucketCntP, count, offs, nbr, pairs, N, Npad, NBUK);

    // ---- layer 1: agg (fp8 gather) + GEMM (writes h bf16 AND h8 fp8) ----
    agg1_kernel<<<(N + 3) / 4, 256, 0, stream>>>(x8, nbr, offs, count, agg1b, N);
    sage_gemm_mfma<2 * IN_CH, true, true, true><<<(N + 127) / 128, 512, 0, stream>>>(
        agg1b, xb, Wt1, b1, h, h8, N);

    // ---- layer 2: agg (fp8 gather) + GEMM (writes z8 fp8 only) ----
    agg2_kernel<<<(N + 3) / 4, 256, 0, stream>>>(h8, nbr, offs, count, agg2b, N);
    sage_gemm_mfma<2 * HID, false, false, true><<<(N + 127) / 128, 512, 0, stream>>>(
        agg2b, h, Wt2, b2, h /*unused*/, z8, N);

    // ---- decode (fp8 z) ----
    decode2_kernel<<<(N + 3) / 4, 256, 0, stream>>>(z8, pairs, offs + Npad, count + Npad, out, N);
}